// Round 6
// baseline (252.905 us; speedup 1.0000x reference)
//
#include <hip/hip_runtime.h>

#define D 48
#define BSH 8            // 256 nodes per bucket
#define BN 256
#define NBMAX 400        // >= NB = 391
#define CH 256           // chunks for the counting partition
#define CAPT 5120        // max edges per bucket in LDS (mean 4092, sd ~64)

// ---------------- front: per-chunk hist + atomic reservation, plus f32->bf16 cvt ----------------

static __device__ inline unsigned int f2bf_rne(float x) {
    unsigned int u = __float_as_uint(x);
    return (u + 0x7FFFu + ((u >> 16) & 1u)) >> 16;
}
static __device__ inline unsigned int pack2(float lo, float hi) {
    return f2bf_rne(lo) | (f2bf_rne(hi) << 16);
}
static __device__ inline float bf_lo(unsigned int u) { return __uint_as_float(u << 16); }
static __device__ inline float bf_hi(unsigned int u) { return __uint_as_float(u & 0xFFFF0000u); }

__global__ void k_front(const int* __restrict__ dst, const float* __restrict__ feat,
                        unsigned int* __restrict__ featb, int* __restrict__ btot,
                        int* __restrict__ cbase, int E, int NB, int CHE, int n4) {
    int t = threadIdx.x;
    if (blockIdx.x < CH) {
        int c = blockIdx.x;
        __shared__ int h[NBMAX];
        for (int b = t; b < NB; b += 1024) h[b] = 0;
        __syncthreads();
        int lo = c * CHE, hi = min(lo + CHE, E);
        for (int i = lo + t; i < hi; i += 1024)
            atomicAdd(&h[dst[i] >> BSH], 1);
        __syncthreads();
        for (int b = t; b < NB; b += 1024)
            cbase[c * NB + b] = atomicAdd(&btot[b], h[b]);   // reserve range in bucket
    } else {
        // cvt: one float4 -> uint2, grid-stride over remaining 256 blocks
        int i = (blockIdx.x - CH) * 1024 + t;
        int stride = 256 * 1024;
        for (; i < n4; i += stride) {
            float4 v = ((const float4*)feat)[i];
            ((uint2*)featb)[i] = make_uint2(pack2(v.x, v.y), pack2(v.z, v.w));
        }
    }
}

// ---------------- scan bucket totals -> bucket bases ----------------

__global__ void k_bscan(const int* __restrict__ btot, int* __restrict__ bbase,
                        int* __restrict__ row_ptr, int NB, int N, int E) {
    __shared__ int sh[256];
    __shared__ int srun;
    int t = threadIdx.x;
    if (t == 0) srun = 0;
    __syncthreads();
    int nch = (NB + 255) / 256;
    for (int c = 0; c < nch; c++) {
        int b = c * 256 + t;
        int v = (b < NB) ? btot[b] : 0;
        sh[t] = v;
        __syncthreads();
        for (int off = 1; off < 256; off <<= 1) {
            int u = (t >= off) ? sh[t - off] : 0;
            __syncthreads();
            sh[t] += u;
            __syncthreads();
        }
        int run = srun;
        if (b < NB) bbase[b] = run + sh[t] - v;
        __syncthreads();
        if (t == 255) srun = run + sh[255];
        __syncthreads();
    }
    if (t == 0) { bbase[NB] = E; row_ptr[N] = E; }
}

// ---------------- scatter to bucket-partitioned stage (LDS cursors only) ----------------

__global__ void k_scatter(const int* __restrict__ src, const int* __restrict__ dst,
                          const int* __restrict__ bbase, const int* __restrict__ cbase,
                          int* __restrict__ stage, int E, int NB, int CHE) {
    int c = blockIdx.x;
    int t = threadIdx.x;
    __shared__ int cur[NBMAX];
    for (int b = t; b < NB; b += blockDim.x)
        cur[b] = bbase[b] + cbase[c * NB + b];
    __syncthreads();
    int lo = c * CHE, hi = min(lo + CHE, E);
    for (int i = lo + t; i < hi; i += blockDim.x) {
        int s = src[i], d = dst[i];
        int p = atomicAdd(&cur[d >> BSH], 1);
        stage[p] = ((d & (BN - 1)) << 17) | s;
    }
}

// ---------------- per-bucket node sort + row_ptr + degree-class perm ----------------

__global__ void k_build(const int* __restrict__ stage, const int* __restrict__ bbase,
                        int* __restrict__ row_ptr, int* __restrict__ esrc,
                        int* __restrict__ perm, int N, int NB) {
    int b = blockIdx.x;
    int t = threadIdx.x;  // 256
    __shared__ int lbuf[CAPT];
    __shared__ int lout[CAPT];
    __shared__ int hist[BN];
    __shared__ int cur[BN];
    __shared__ int sh[BN];
    __shared__ int dh[64];
    __shared__ int dcur[64];
    int base = bbase[b];
    int cnt = min(bbase[b + 1] - base, CAPT);
    hist[t] = 0;
    if (t < 64) dh[t] = 0;
    __syncthreads();
    for (int i = t; i < cnt; i += 256) {
        int v = stage[base + i];
        lbuf[i] = v;
        atomicAdd(&hist[v >> 17], 1);
    }
    __syncthreads();
    int orig = hist[t];
    sh[t] = orig;
    __syncthreads();
    for (int off = 1; off < 256; off <<= 1) {
        int u = (t >= off) ? sh[t - off] : 0;
        __syncthreads();
        sh[t] += u;
        __syncthreads();
    }
    int excl = sh[t] - orig;
    cur[t] = excl;
    int node = (b << BSH) + t;
    if (node < N) row_ptr[node] = base + excl;
    // degree-class histogram (invalid nodes also classed so perm is fully written)
    int dcls = min(orig, 63);
    atomicAdd(&dh[dcls], 1);
    __syncthreads();
    // wave-scan of 64 class counts (threads 0..63 are wave 0)
    if (t < 64) {
        int v = dh[t];
        int x = v;
#pragma unroll
        for (int off = 1; off < 64; off <<= 1) {
            int u = __shfl_up(x, off);
            if (t >= off) x += u;
        }
        dcur[t] = x - v;   // exclusive prefix
    }
    __syncthreads();
    int pos = atomicAdd(&dcur[dcls], 1);
    perm[(b << BSH) + pos] = node;   // node may be >= N; pull guards
    __syncthreads();
    for (int i = t; i < cnt; i += 256) {
        int v = lbuf[i];
        int p = atomicAdd(&cur[v >> 17], 1);
        lout[p] = v & 0x1FFFF;
    }
    __syncthreads();
    for (int i = t; i < cnt; i += 256) esrc[base + i] = lout[i];
}

// ---------------- pull-mode aggregation, bf16 rows, degree-binned via perm ----------------
// 8 lanes per node; lane l owns uints {2l,2l+1} and uint {16+l}. 96B/row, 2 lines/edge.

template <int RELU, int OUTF32>
__global__ void k_pull(const unsigned int* __restrict__ hin, void* __restrict__ hout,
                       const int* __restrict__ row_ptr, const int* __restrict__ esrc,
                       const int* __restrict__ perm, int n) {
    int grp = threadIdx.x >> 3;
    int lane = threadIdx.x & 7;
    int node = perm[blockIdx.x * 32 + grp];
    if (node >= n) return;
    int jb = row_ptr[node], je = row_ptr[node + 1];
    float a0 = 0.f, a1 = 0.f, a2 = 0.f, a3 = 0.f, a4 = 0.f, a5 = 0.f;
    int j = jb;
    int je8 = jb + ((je - jb) & ~7);
    for (; j < je8; j += 8) {
        int s[8];
#pragma unroll
        for (int u = 0; u < 8; u++) s[u] = esrc[j + u];
        uint2 q[8];
        unsigned int w[8];
#pragma unroll
        for (int u = 0; u < 8; u++) {
            const unsigned int* r = hin + s[u] * 24;
            q[u] = *(const uint2*)(r + 2 * lane);
            w[u] = r[16 + lane];
        }
#pragma unroll
        for (int u = 0; u < 8; u++) {
            a0 += bf_lo(q[u].x); a1 += bf_hi(q[u].x);
            a2 += bf_lo(q[u].y); a3 += bf_hi(q[u].y);
            a4 += bf_lo(w[u]);   a5 += bf_hi(w[u]);
        }
    }
    for (; j < je; ++j) {
        int s0 = esrc[j];
        const unsigned int* r = hin + s0 * 24;
        uint2 q0 = *(const uint2*)(r + 2 * lane);
        unsigned int w0 = r[16 + lane];
        a0 += bf_lo(q0.x); a1 += bf_hi(q0.x);
        a2 += bf_lo(q0.y); a3 += bf_hi(q0.y);
        a4 += bf_lo(w0);   a5 += bf_hi(w0);
    }
    if (RELU) {
        a0 = fmaxf(a0, 0.f); a1 = fmaxf(a1, 0.f); a2 = fmaxf(a2, 0.f);
        a3 = fmaxf(a3, 0.f); a4 = fmaxf(a4, 0.f); a5 = fmaxf(a5, 0.f);
    }
    if (OUTF32) {
        float* o = (float*)hout + (size_t)node * D;
        *(float4*)(o + 4 * lane) = make_float4(a0, a1, a2, a3);
        *(float2*)(o + 32 + 2 * lane) = make_float2(a4, a5);
    } else {
        unsigned int* o = (unsigned int*)hout + node * 24;
        *(uint2*)(o + 2 * lane) = make_uint2(pack2(a0, a1), pack2(a2, a3));
        o[16 + lane] = pack2(a4, a5);
    }
}

extern "C" void kernel_launch(void* const* d_in, const int* in_sizes, int n_in,
                              void* d_out, int out_size, void* d_ws, size_t ws_size,
                              hipStream_t stream) {
    const float* feat = (const float*)d_in[0];
    const int* src = (const int*)d_in[1];
    const int* dst = (const int*)d_in[2];
    int N = in_sizes[0] / D;              // 100000
    int E = in_sizes[1];                  // 1600000
    int NB = (N + BN - 1) >> BSH;         // 391
    int CHE = (E + CH - 1) / CH;          // 6250
    int n4 = N * D / 4;

    char* ws = (char*)d_ws;
    // layout: btot@0, bbase@64K, cbase@128K(400K), row_ptr@640K(400K),
    // perm@1152K(400K), esrc@2M(6.4M), stage@10M(6.4M), featb@17M(9.6M),
    // hb0@27M(9.6M) -> peak 36.6MB
    int*   btot    = (int*)(ws + ((size_t)0 << 10));
    int*   bbase   = (int*)(ws + ((size_t)64 << 10));
    int*   cbase   = (int*)(ws + ((size_t)128 << 10));
    int*   row_ptr = (int*)(ws + ((size_t)640 << 10));
    int*   perm    = (int*)(ws + ((size_t)1152 << 10));
    int*   esrc    = (int*)(ws + ((size_t)2 << 20));
    int*   stage   = (int*)(ws + ((size_t)10 << 20));
    unsigned int* featb = (unsigned int*)(ws + ((size_t)17 << 20));
    unsigned int* hb0   = (unsigned int*)(ws + ((size_t)27 << 20));

    hipMemsetAsync(btot, 0, (size_t)NB * sizeof(int), stream);

    k_front<<<CH + 256, 1024, 0, stream>>>(dst, feat, featb, btot, cbase, E, NB, CHE, n4);
    k_bscan<<<1, 256, 0, stream>>>(btot, bbase, row_ptr, NB, N, E);
    k_scatter<<<CH, 1024, 0, stream>>>(src, dst, bbase, cbase, stage, E, NB, CHE);
    k_build<<<NB, 256, 0, stream>>>(stage, bbase, row_ptr, esrc, perm, N, NB);

    int pg = NB * 8;   // covers all NB*256 perm slots, 32 nodes per block
    k_pull<1, 0><<<pg, 256, 0, stream>>>(featb, hb0, row_ptr, esrc, perm, N);   // L1
    k_pull<1, 0><<<pg, 256, 0, stream>>>(hb0, featb, row_ptr, esrc, perm, N);   // L2
    k_pull<0, 1><<<pg, 256, 0, stream>>>(featb, d_out, row_ptr, esrc, perm, N); // L3 (f32)
}

// Round 7
// 204.979 us; speedup vs baseline: 1.2338x; 1.2338x over previous
//
#include <hip/hip_runtime.h>

#define D 48
#define BSH 8            // 256 nodes per bucket
#define BN 256
#define NBMAX 400        // >= NB = 391
#define CH 256           // chunks for the counting partition
#define CAPT 5120        // max edges per bucket in LDS (mean 4092, sd ~64)

// bf16 helpers
static __device__ inline unsigned int f2bf_rne(float x) {
    unsigned int u = __float_as_uint(x);
    return (u + 0x7FFFu + ((u >> 16) & 1u)) >> 16;
}
static __device__ inline unsigned int pack2(float lo, float hi) {
    return f2bf_rne(lo) | (f2bf_rne(hi) << 16);
}
static __device__ inline float bf_lo(unsigned int u) { return __uint_as_float(u << 16); }
static __device__ inline float bf_hi(unsigned int u) { return __uint_as_float(u & 0xFFFF0000u); }

// ---------------- front: per-chunk hist + atomic reservation, fused f32->bf16 cvt ----------------
// cvt writes PADDED rows: 32 uints (128B) per node, uints 24..31 zeroed.

__global__ void k_front(const int* __restrict__ dst, const float* __restrict__ feat,
                        uint2* __restrict__ featb, int* __restrict__ btot,
                        int* __restrict__ cbase, int E, int NB, int CHE, int N) {
    int t = threadIdx.x;
    if (blockIdx.x < CH) {
        int c = blockIdx.x;
        __shared__ int h[NBMAX];
        for (int b = t; b < NB; b += 1024) h[b] = 0;
        __syncthreads();
        int lo = c * CHE, hi = min(lo + CHE, E);
        for (int i = lo + t; i < hi; i += 1024)
            atomicAdd(&h[dst[i] >> BSH], 1);
        __syncthreads();
        for (int b = t; b < NB; b += 1024)
            cbase[c * NB + b] = atomicAdd(&btot[b], h[b]);   // reserve range in bucket
    } else {
        // padded cvt: i indexes uint2 slots; row = 16 uint2; slots 12..15 are zero pad
        const float4* f4 = (const float4*)feat;
        int total = N * 16;
        int i = (blockIdx.x - CH) * 1024 + t;
        int stride = 256 * 1024;
        for (; i < total; i += stride) {
            int node = i >> 4, c = i & 15;
            uint2 v = make_uint2(0u, 0u);
            if (c < 12) {
                float4 f = f4[node * 12 + c];
                v = make_uint2(pack2(f.x, f.y), pack2(f.z, f.w));
            }
            featb[i] = v;
        }
    }
}

// ---------------- scan bucket totals -> bucket bases ----------------

__global__ void k_bscan(const int* __restrict__ btot, int* __restrict__ bbase,
                        int* __restrict__ row_ptr, int NB, int N, int E) {
    __shared__ int sh[256];
    __shared__ int srun;
    int t = threadIdx.x;
    if (t == 0) srun = 0;
    __syncthreads();
    int nch = (NB + 255) / 256;
    for (int c = 0; c < nch; c++) {
        int b = c * 256 + t;
        int v = (b < NB) ? btot[b] : 0;
        sh[t] = v;
        __syncthreads();
        for (int off = 1; off < 256; off <<= 1) {
            int u = (t >= off) ? sh[t - off] : 0;
            __syncthreads();
            sh[t] += u;
            __syncthreads();
        }
        int run = srun;
        if (b < NB) bbase[b] = run + sh[t] - v;
        __syncthreads();
        if (t == 255) srun = run + sh[255];
        __syncthreads();
    }
    if (t == 0) { bbase[NB] = E; row_ptr[N] = E; }
}

// ---------------- scatter to bucket-partitioned stage (LDS cursors only) ----------------

__global__ void k_scatter(const int* __restrict__ src, const int* __restrict__ dst,
                          const int* __restrict__ bbase, const int* __restrict__ cbase,
                          int* __restrict__ stage, int E, int NB, int CHE) {
    int c = blockIdx.x;
    int t = threadIdx.x;
    __shared__ int cur[NBMAX];
    for (int b = t; b < NB; b += blockDim.x)
        cur[b] = bbase[b] + cbase[c * NB + b];
    __syncthreads();
    int lo = c * CHE, hi = min(lo + CHE, E);
    for (int i = lo + t; i < hi; i += blockDim.x) {
        int s = src[i], d = dst[i];
        int p = atomicAdd(&cur[d >> BSH], 1);
        stage[p] = ((d & (BN - 1)) << 17) | s;
    }
}

// ---------------- per-bucket node sort + row_ptr (identity order, no perm) ----------------

__global__ void k_build(const int* __restrict__ stage, const int* __restrict__ bbase,
                        int* __restrict__ row_ptr, int* __restrict__ esrc,
                        int N, int NB) {
    int b = blockIdx.x;
    int t = threadIdx.x;  // 256
    __shared__ int lbuf[CAPT];
    __shared__ int lout[CAPT];
    __shared__ int hist[BN];
    __shared__ int cur[BN];
    __shared__ int sh[BN];
    int base = bbase[b];
    int cnt = min(bbase[b + 1] - base, CAPT);
    hist[t] = 0;
    __syncthreads();
    for (int i = t; i < cnt; i += 256) {
        int v = stage[base + i];
        lbuf[i] = v;
        atomicAdd(&hist[v >> 17], 1);
    }
    __syncthreads();
    int orig = hist[t];
    sh[t] = orig;
    __syncthreads();
    for (int off = 1; off < 256; off <<= 1) {
        int u = (t >= off) ? sh[t - off] : 0;
        __syncthreads();
        sh[t] += u;
        __syncthreads();
    }
    int excl = sh[t] - orig;
    cur[t] = excl;
    int node = (b << BSH) + t;
    if (node < N) row_ptr[node] = base + excl;
    __syncthreads();
    for (int i = t; i < cnt; i += 256) {
        int v = lbuf[i];
        int p = atomicAdd(&cur[v >> 17], 1);
        lout[p] = v & 0x1FFFF;
    }
    __syncthreads();
    for (int i = t; i < cnt; i += 256) esrc[base + i] = lout[i];
}

// ---------------- pull: 16 lanes/node, 2 edges per step, uint4 loads on 128B rows ----------------
// lane = side*8 + sub; side s takes edge j+s; lane loads row uint4 #sub (16B).
// Lane accumulates 8 bf16 feats (8*sub .. 8*sub+7); epilogue shfl_xor(8) merges sides.
// Rows padded to 128B with zeros -> subs 6,7 accumulate zeros and store zeros.

template <int RELU, int OUTF32>
__global__ void k_pull(const uint4* __restrict__ hin, void* __restrict__ hout,
                       const int* __restrict__ row_ptr, const int* __restrict__ esrc,
                       int n) {
    int grp = threadIdx.x >> 4;          // 16 nodes per 256-block
    int lane = threadIdx.x & 15;
    int side = lane >> 3;
    int sub = lane & 7;
    int node = blockIdx.x * 16 + grp;
    if (node >= n) return;
    int jb = row_ptr[node], je = row_ptr[node + 1];
    float a0 = 0.f, a1 = 0.f, a2 = 0.f, a3 = 0.f, a4 = 0.f, a5 = 0.f, a6 = 0.f, a7 = 0.f;
    int j = jb;
    // unrolled: 4 pairs = 8 edges per trip
    for (; j + 8 <= je; j += 8) {
        int s0 = esrc[j + 0 + side];
        int s1 = esrc[j + 2 + side];
        int s2 = esrc[j + 4 + side];
        int s3 = esrc[j + 6 + side];
        uint4 q0 = hin[s0 * 8 + sub];
        uint4 q1 = hin[s1 * 8 + sub];
        uint4 q2 = hin[s2 * 8 + sub];
        uint4 q3 = hin[s3 * 8 + sub];
        a0 += bf_lo(q0.x); a1 += bf_hi(q0.x); a2 += bf_lo(q0.y); a3 += bf_hi(q0.y);
        a4 += bf_lo(q0.z); a5 += bf_hi(q0.z); a6 += bf_lo(q0.w); a7 += bf_hi(q0.w);
        a0 += bf_lo(q1.x); a1 += bf_hi(q1.x); a2 += bf_lo(q1.y); a3 += bf_hi(q1.y);
        a4 += bf_lo(q1.z); a5 += bf_hi(q1.z); a6 += bf_lo(q1.w); a7 += bf_hi(q1.w);
        a0 += bf_lo(q2.x); a1 += bf_hi(q2.x); a2 += bf_lo(q2.y); a3 += bf_hi(q2.y);
        a4 += bf_lo(q2.z); a5 += bf_hi(q2.z); a6 += bf_lo(q2.w); a7 += bf_hi(q2.w);
        a0 += bf_lo(q3.x); a1 += bf_hi(q3.x); a2 += bf_lo(q3.y); a3 += bf_hi(q3.y);
        a4 += bf_lo(q3.z); a5 += bf_hi(q3.z); a6 += bf_lo(q3.w); a7 += bf_hi(q3.w);
    }
    for (; j + 2 <= je; j += 2) {
        int s0 = esrc[j + side];
        uint4 q0 = hin[s0 * 8 + sub];
        a0 += bf_lo(q0.x); a1 += bf_hi(q0.x); a2 += bf_lo(q0.y); a3 += bf_hi(q0.y);
        a4 += bf_lo(q0.z); a5 += bf_hi(q0.z); a6 += bf_lo(q0.w); a7 += bf_hi(q0.w);
    }
    if (j < je && side == 0) {   // last odd edge: side 0 only
        int s0 = esrc[j];
        uint4 q0 = hin[s0 * 8 + sub];
        a0 += bf_lo(q0.x); a1 += bf_hi(q0.x); a2 += bf_lo(q0.y); a3 += bf_hi(q0.y);
        a4 += bf_lo(q0.z); a5 += bf_hi(q0.z); a6 += bf_lo(q0.w); a7 += bf_hi(q0.w);
    }
    // merge the two sides (lane ^ 8 is within the same 16-lane group)
    a0 += __shfl_xor(a0, 8); a1 += __shfl_xor(a1, 8);
    a2 += __shfl_xor(a2, 8); a3 += __shfl_xor(a3, 8);
    a4 += __shfl_xor(a4, 8); a5 += __shfl_xor(a5, 8);
    a6 += __shfl_xor(a6, 8); a7 += __shfl_xor(a7, 8);
    if (RELU) {
        a0 = fmaxf(a0, 0.f); a1 = fmaxf(a1, 0.f); a2 = fmaxf(a2, 0.f); a3 = fmaxf(a3, 0.f);
        a4 = fmaxf(a4, 0.f); a5 = fmaxf(a5, 0.f); a6 = fmaxf(a6, 0.f); a7 = fmaxf(a7, 0.f);
    }
    if (side != 0) return;
    if (OUTF32) {
        if (sub < 6) {
            float* o = (float*)hout + (size_t)node * D + 8 * sub;
            *(float4*)(o)     = make_float4(a0, a1, a2, a3);
            *(float4*)(o + 4) = make_float4(a4, a5, a6, a7);
        }
    } else {
        uint4* o = (uint4*)hout + node * 8 + sub;
        *o = make_uint4(pack2(a0, a1), pack2(a2, a3), pack2(a4, a5), pack2(a6, a7));
    }
}

extern "C" void kernel_launch(void* const* d_in, const int* in_sizes, int n_in,
                              void* d_out, int out_size, void* d_ws, size_t ws_size,
                              hipStream_t stream) {
    const float* feat = (const float*)d_in[0];
    const int* src = (const int*)d_in[1];
    const int* dst = (const int*)d_in[2];
    int N = in_sizes[0] / D;              // 100000
    int E = in_sizes[1];                  // 1600000
    int NB = (N + BN - 1) >> BSH;         // 391
    int CHE = (E + CH - 1) / CH;          // 6250

    char* ws = (char*)d_ws;
    // layout: btot@0, bbase@64K, cbase@128K(400K), row_ptr@640K(400K),
    // esrc@2M(6.4M), featb@9M(12.8M), stage@22M(6.4M), hb0@22M(12.8M, aliases
    // dead stage after k_build) -> peak 34.8MB
    int*   btot    = (int*)(ws + ((size_t)0 << 10));
    int*   bbase   = (int*)(ws + ((size_t)64 << 10));
    int*   cbase   = (int*)(ws + ((size_t)128 << 10));
    int*   row_ptr = (int*)(ws + ((size_t)640 << 10));
    int*   esrc    = (int*)(ws + ((size_t)2 << 20));
    uint2* featb   = (uint2*)(ws + ((size_t)9 << 20));
    int*   stage   = (int*)(ws + ((size_t)22 << 20));
    uint4* hb0     = (uint4*)(ws + ((size_t)22 << 20));

    hipMemsetAsync(btot, 0, (size_t)NB * sizeof(int), stream);

    k_front<<<CH + 256, 1024, 0, stream>>>(dst, feat, featb, btot, cbase, E, NB, CHE, N);
    k_bscan<<<1, 256, 0, stream>>>(btot, bbase, row_ptr, NB, N, E);
    k_scatter<<<CH, 1024, 0, stream>>>(src, dst, bbase, cbase, stage, E, NB, CHE);
    k_build<<<NB, 256, 0, stream>>>(stage, bbase, row_ptr, esrc, N, NB);

    int pg = (N + 15) / 16;
    k_pull<1, 0><<<pg, 256, 0, stream>>>((const uint4*)featb, hb0, row_ptr, esrc, N);  // L1
    k_pull<1, 0><<<pg, 256, 0, stream>>>((const uint4*)hb0, featb, row_ptr, esrc, N);  // L2
    k_pull<0, 1><<<pg, 256, 0, stream>>>((const uint4*)featb, d_out, row_ptr, esrc, N); // L3 (f32)
}